// Round 11
// baseline (119.055 us; speedup 1.0000x reference)
//
#include <hip/hip_runtime.h>

// Moreau-tropical forward, round 11: r8's VMEM-fed register tile + explicit
// double-buffered k-loop prefetch (fixes r8's diagnosed load serialization:
// VGPR_Count=64 -> no loads in flight -> 200cyc L2 latency exposed per k).
//
// z = x[b] + W[n] (D=1024); root of f(tau)=sum relu(z-tau)=lam in [M-lam, M],
// M = max(z); only z > M-lam contribute. Block = 8b x 8n = 64 pairs, 256 thr;
// wave = 2x2 quadrant, lane owns 16 d's (k*256 + lane*4). Pass 1: k-loop with
// cur/nxt float4 buffers - next k's 8 loads issue BEFORE current k's 128 VALU
// ops consume cur (compute 256 cyc > L2 200 cyc -> hidden). 16 independent
// 6-step shfl reduce chains (ILP-overlapped). Pass 2: per-(thread,pair) exact
// gate m[q] > thr, gated reloads (L1/L2-hot), rare atomic inserts. Solve: one
// wave, thread-per-pair register bisection (proven r4-r10, absmax 0.0).
// Only 2 barriers; LDS 6.8 KB; grid 1024 = 4 blocks/CU, 16 waves/CU.

#define D_DIM   1024
#define TB      8
#define TN      8
#define NPAIR   64
#define NTHR    256
#define CAPP    24
#define NB      16
#define NEG_INF (-3.0e38f)

__global__ void __launch_bounds__(NTHR, 4)
moreau_tropical(const float* __restrict__ x, const float* __restrict__ W,
                const float* __restrict__ lam_p, float* __restrict__ out,
                int B, int N) {
    __shared__ float cand[CAPP * NPAIR];   // cand[slot*64 + p]: conflict-free
    __shared__ float pmax[NPAIR];
    __shared__ int   pcnt[NPAIR];

    const int tid  = threadIdx.x;
    const int lane = tid & 63;
    const int wq   = tid >> 6;             // wave -> 2x2 quadrant
    const int tb   = wq >> 1;
    const int tn   = wq & 1;
    const int b0   = blockIdx.y * TB;
    const int n0   = blockIdx.x * TN;
    const float lam = lam_p[0];

    if (tid < NPAIR) pcnt[tid] = 0;

    const float* xr[4];
    const float* wr[4];
#pragma unroll
    for (int i = 0; i < 4; ++i)
        xr[i] = x + (size_t)min(b0 + tb * 4 + i, B - 1) * D_DIM + lane * 4;
#pragma unroll
    for (int j = 0; j < 4; ++j)
        wr[j] = W + (size_t)min(n0 + tn * 4 + j, N - 1) * D_DIM + lane * 4;

    // ---- pass 1: 4x4 register tile, double-buffered k-loop ----
    float m[16];
#pragma unroll
    for (int q = 0; q < 16; ++q) m[q] = NEG_INF;

    float4 xc[4], wc[4], xn[4], wn[4];
#pragma unroll
    for (int i = 0; i < 4; ++i) xc[i] = *(const float4*)(xr[i]);
#pragma unroll
    for (int j = 0; j < 4; ++j) wc[j] = *(const float4*)(wr[j]);

#pragma unroll
    for (int k = 0; k < 4; ++k) {
        // prefetch k+1 BEFORE consuming k (hides ~200cyc L2 under 128 VALU ops)
        if (k < 3) {
#pragma unroll
            for (int i = 0; i < 4; ++i) xn[i] = *(const float4*)(xr[i] + (k + 1) * 256);
#pragma unroll
            for (int j = 0; j < 4; ++j) wn[j] = *(const float4*)(wr[j] + (k + 1) * 256);
        }
#pragma unroll
        for (int i = 0; i < 4; ++i)
#pragma unroll
            for (int j = 0; j < 4; ++j) {
                const float4 a = xc[i], c = wc[j];
                const float z0 = a.x + c.x, z1 = a.y + c.y;
                const float z2 = a.z + c.z, z3 = a.w + c.w;
                m[i * 4 + j] = fmaxf(m[i * 4 + j],
                                     fmaxf(fmaxf(z0, z1), fmaxf(z2, z3)));
            }
        if (k < 3) {
#pragma unroll
            for (int i = 0; i < 4; ++i) xc[i] = xn[i];
#pragma unroll
            for (int j = 0; j < 4; ++j) wc[j] = wn[j];
        }
    }

    // ---- per-pair max: 16 independent 6-step shfl chains (ILP) ----
#pragma unroll
    for (int q = 0; q < 16; ++q) {
        float v = m[q];
#pragma unroll
        for (int o = 1; o < 64; o <<= 1) v = fmaxf(v, __shfl_xor(v, o, 64));
        if (lane == 0)
            pmax[(tb * 4 + (q >> 2)) * 8 + tn * 4 + (q & 3)] = v;
    }
    __syncthreads();

    // ---- pass 2: exact per-(thread,pair) gate, gated L2-hot reloads ----
#pragma unroll
    for (int q = 0; q < 16; ++q) {
        const int i = q >> 2, j = q & 3;
        const int p = (tb * 4 + i) * 8 + tn * 4 + j;
        const float thr = pmax[p] - lam;
        if (m[q] > thr) {        // ~1-3 lanes per pair enter
#pragma unroll
            for (int k = 0; k < 4; ++k) {
                const float4 a = *(const float4*)(xr[i] + k * 256);
                const float4 c = *(const float4*)(wr[j] + k * 256);
                const float z0 = a.x + c.x, z1 = a.y + c.y;
                const float z2 = a.z + c.z, z3 = a.w + c.w;
                if (z0 > thr) { int s_ = atomicAdd(&pcnt[p], 1); if (s_ < CAPP) cand[s_ * NPAIR + p] = z0; }
                if (z1 > thr) { int s_ = atomicAdd(&pcnt[p], 1); if (s_ < CAPP) cand[s_ * NPAIR + p] = z1; }
                if (z2 > thr) { int s_ = atomicAdd(&pcnt[p], 1); if (s_ < CAPP) cand[s_ * NPAIR + p] = z2; }
                if (z3 > thr) { int s_ = atomicAdd(&pcnt[p], 1); if (s_ < CAPP) cand[s_ * NPAIR + p] = z3; }
            }
        }
    }
    __syncthreads();

    // ---- solve: one wave, thread-per-pair (proven rounds 4-10) ----
    if (tid < NPAIR) {
        const int p  = tid;
        const int pb = p >> 3;
        const int pn = p & 7;
        const int K  = pcnt[p];
        const float M    = pmax[p];
        const float thr0 = M - lam;
        float tau, delta;

        if (K <= CAPP) {
            int Kw = K;
#pragma unroll
            for (int o = 1; o < 64; o <<= 1) Kw = max(Kw, __shfl_xor(Kw, o, 64));

            float lo = thr0, hi = M;
            for (int it = 0; it < NB; ++it) {
                const float mid = 0.5f * (lo + hi);
                float f = 0.0f;
                for (int j = 0; j < Kw; ++j) {
                    float v = cand[j * NPAIR + p];
                    v = (j < K) ? v : NEG_INF;
                    f += fmaxf(v - mid, 0.0f);
                }
                if (f > lam) lo = mid; else hi = mid;
            }
            tau = 0.5f * (lo + hi);
            float s2 = 0.0f;
            for (int j = 0; j < Kw; ++j) {
                float v = cand[j * NPAIR + p];
                v = (j < K) ? v : NEG_INF;
                const float t = fmaxf(v - tau, 0.0f);
                s2 += t * t;
            }
            delta = s2 / (2.0f * lam);
        } else {
            // overflow fallback (~never): stream rows from global (L2-hot)
            const float* xrow = x + (size_t)min(b0 + pb, B - 1) * D_DIM;
            const float* wrow = W + (size_t)min(n0 + pn, N - 1) * D_DIM;
            float lo = thr0, hi = M;
            for (int it = 0; it < NB; ++it) {
                const float mid = 0.5f * (lo + hi);
                float f = 0.0f;
                for (int d = 0; d < D_DIM; ++d)
                    f += fmaxf(xrow[d] + wrow[d] - mid, 0.0f);
                if (f > lam) lo = mid; else hi = mid;
            }
            tau = 0.5f * (lo + hi);
            float s2 = 0.0f;
            for (int d = 0; d < D_DIM; ++d) {
                const float t = fmaxf(xrow[d] + wrow[d] - tau, 0.0f);
                s2 += t * t;
            }
            delta = s2 / (2.0f * lam);
        }

        const int ob = min(b0 + pb, B - 1);
        const int on = min(n0 + pn, N - 1);
        out[(size_t)ob * N + on] = tau + delta;
    }
}

extern "C" void kernel_launch(void* const* d_in, const int* in_sizes, int n_in,
                              void* d_out, int out_size, void* d_ws, size_t ws_size,
                              hipStream_t stream) {
    const float* x    = (const float*)d_in[0];
    const float* W    = (const float*)d_in[1];
    const float* lamp = (const float*)d_in[2];
    float* out        = (float*)d_out;

    const int B = in_sizes[0] / D_DIM;
    const int N = in_sizes[1] / D_DIM;

    dim3 grid((N + TN - 1) / TN, (B + TB - 1) / TB);
    moreau_tropical<<<grid, NTHR, 0, stream>>>(x, W, lamp, out, B, N);
}